// Round 1
// baseline (5715.163 us; speedup 1.0000x reference)
//
#include <hip/hip_runtime.h>

#define E_EDGES 640000
#define NN 20000
#define NC 16

#define Y00F 0.28209479177387814f
#define Y1CF 0.4886025119029199f
#define RS3  0.5773502691896258f
#define RS2  0.7071067811865476f

// ---- init: copy coords passthrough, zero accumulator region ----
__global__ void init_out(const float* __restrict__ coords,
                         float* __restrict__ out, int out_size) {
    int i = blockIdx.x * blockDim.x + threadIdx.x;
    if (i < 3 * NN) {
        out[i] = coords[i];
    } else if (i < out_size) {
        out[i] = 0.0f;
    }
}

// ---- main: one thread per edge, loop channels, atomic scatter ----
__global__ __launch_bounds__(256) void tp_edges(
    const float* __restrict__ edges,
    const int*   __restrict__ senders,
    const int*   __restrict__ receivers,
    const float* __restrict__ nodes0,
    const float* __restrict__ nodes1,
    const float* __restrict__ c00, const float* __restrict__ c01,
    const float* __restrict__ c10, const float* __restrict__ c11,
    const float* __restrict__ w000, const float* __restrict__ w011,
    const float* __restrict__ w101, const float* __restrict__ w110,
    const float* __restrict__ w111,
    float* __restrict__ out0,   // [NN, 32]
    float* __restrict__ out1)   // [NN, 48, 3]
{
    // LDS constants: 4 coeff sets [16,5] = 320 floats, 5 weight sets [16] = 80 floats
    __shared__ float sc[400];
    for (int i = threadIdx.x; i < 400; i += blockDim.x) {
        float v;
        if      (i < 80)  v = c00[i];
        else if (i < 160) v = c01[i - 80];
        else if (i < 240) v = c10[i - 160];
        else if (i < 320) v = c11[i - 240];
        else if (i < 336) v = w000[i - 320];
        else if (i < 352) v = w011[i - 336];
        else if (i < 368) v = w101[i - 352];
        else if (i < 384) v = w110[i - 368];
        else              v = w111[i - 384];
        sc[i] = v;
    }
    __syncthreads();

    int e = blockIdx.x * blockDim.x + threadIdx.x;
    if (e >= E_EDGES) return;

    float ex = edges[3 * e + 0];
    float ey = edges[3 * e + 1];
    float ez = edges[3 * e + 2];
    float r = sqrtf(ex * ex + ey * ey + ez * ez);

    // RBFs: centers = 0, .875, 1.75, 2.625, 3.5 ; spread = 0.7
    float rbf[5];
#pragma unroll
    for (int b = 0; b < 5; b++) {
        float d = r - 0.875f * (float)b;
        rbf[b] = __expf(-0.7f * d * d);
    }

    int s  = senders[e];
    int rc = receivers[e];
    const float* n0p = nodes0 + s * NC;
    const float* n1p = nodes1 + s * NC * 3;
    float* o0 = out0 + rc * (2 * NC);
    float* o1 = out1 + rc * (3 * NC) * 3;

    // direction part of l_f=1 filters, real-basis order (y, z, x)
    const float pey = Y1CF * ey;
    const float pez = Y1CF * ez;
    const float pex = Y1CF * ex;

#pragma unroll 4
    for (int c = 0; c < NC; c++) {
        float rad00 = 0.f, rad01 = 0.f, rad10 = 0.f, rad11 = 0.f;
#pragma unroll
        for (int b = 0; b < 5; b++) {
            float rb = rbf[b];
            rad00 = fmaf(rb, sc[        c * 5 + b], rad00);
            rad01 = fmaf(rb, sc[ 80 +   c * 5 + b], rad01);
            rad10 = fmaf(rb, sc[160 +   c * 5 + b], rad10);
            rad11 = fmaf(rb, sc[240 +   c * 5 + b], rad11);
        }
        float n0  = n0p[c];
        float n1a = n1p[3 * c + 0];
        float n1b = n1p[3 * c + 1];
        float n1c = n1p[3 * c + 2];

        // f11 components (m = 0,1,2)
        float f11a = rad11 * pey;
        float f11b = rad11 * pez;
        float f11c = rad11 * pex;

        // l_o = 0 messages
        float m0A = sc[320 + c] * n0 * rad00 * Y00F;                     // path 000
        float m0B = sc[368 + c] * RS3 *
                    (n1a * f11a + n1b * f11b + n1c * f11c);              // path 110
        atomicAdd(&o0[c],      m0A);
        atomicAdd(&o0[NC + c], m0B);

        // l_o = 1, path 011: w * n0 * f01[o]
        float kA = sc[336 + c] * n0 * rad01;
        atomicAdd(&o1[3 * c + 0], kA * pey);
        atomicAdd(&o1[3 * c + 1], kA * pez);
        atomicAdd(&o1[3 * c + 2], kA * pex);

        // l_o = 1, path 101: w * rad10 * Y00 * n1[o]
        float kB = sc[352 + c] * rad10 * Y00F;
        atomicAdd(&o1[3 * (NC + c) + 0], kB * n1a);
        atomicAdd(&o1[3 * (NC + c) + 1], kB * n1b);
        atomicAdd(&o1[3 * (NC + c) + 2], kB * n1c);

        // l_o = 1, path 111: w/sqrt2 * cross(n1, f11)
        float kC = sc[384 + c] * RS2;
        atomicAdd(&o1[3 * (2 * NC + c) + 0], kC * (n1b * f11c - n1c * f11b));
        atomicAdd(&o1[3 * (2 * NC + c) + 1], kC * (n1c * f11a - n1a * f11c));
        atomicAdd(&o1[3 * (2 * NC + c) + 2], kC * (n1a * f11b - n1b * f11a));
    }
}

extern "C" void kernel_launch(void* const* d_in, const int* in_sizes, int n_in,
                              void* d_out, int out_size, void* d_ws, size_t ws_size,
                              hipStream_t stream) {
    const float* coords    = (const float*)d_in[0];
    const float* nodes0    = (const float*)d_in[1];
    const float* nodes1    = (const float*)d_in[2];
    const float* edges     = (const float*)d_in[3];
    const int*   senders   = (const int*)  d_in[4];
    const int*   receivers = (const int*)  d_in[5];
    const float* c00       = (const float*)d_in[6];
    const float* c01       = (const float*)d_in[7];
    const float* c10       = (const float*)d_in[8];
    const float* c11       = (const float*)d_in[9];
    const float* w000      = (const float*)d_in[10];
    const float* w011      = (const float*)d_in[11];
    const float* w101      = (const float*)d_in[12];
    const float* w110      = (const float*)d_in[13];
    const float* w111      = (const float*)d_in[14];

    float* out  = (float*)d_out;
    float* out0 = out + 3 * NN;                 // new0: [NN, 32]
    float* out1 = out + 3 * NN + NN * 2 * NC;   // new1: [NN, 48, 3]

    {
        int total = out_size;
        int threads = 256;
        int blocks = (total + threads - 1) / threads;
        init_out<<<blocks, threads, 0, stream>>>(coords, out, total);
    }
    {
        int threads = 256;
        int blocks = (E_EDGES + threads - 1) / threads;
        tp_edges<<<blocks, threads, 0, stream>>>(
            edges, senders, receivers, nodes0, nodes1,
            c00, c01, c10, c11, w000, w011, w101, w110, w111,
            out0, out1);
    }
}

// Round 2
// 238.031 us; speedup vs baseline: 24.0102x; 24.0102x over previous
//
#include <hip/hip_runtime.h>

#define E_EDGES 640000
#define NN 20000
#define NC 16

#define Y00F 0.28209479177387814f
#define Y1CF 0.4886025119029199f
#define RS3  0.5773502691896258f
#define RS2  0.7071067811865476f

// ---------------- phase 0: coords passthrough ----------------
__global__ void copy_coords(const float* __restrict__ coords,
                            float* __restrict__ out) {
    int i = blockIdx.x * blockDim.x + threadIdx.x;
    if (i < 3 * NN) out[i] = coords[i];
}

// ---------------- phase 1a: zero hist + cursor ----------------
__global__ void zero_ints(int* __restrict__ p, int n) {
    int i = blockIdx.x * blockDim.x + threadIdx.x;
    if (i < n) p[i] = 0;
}

// ---------------- phase 1b: receiver histogram ----------------
__global__ void hist_kernel(const int* __restrict__ receivers,
                            int* __restrict__ hist) {
    int e = blockIdx.x * blockDim.x + threadIdx.x;
    if (e < E_EDGES) atomicAdd(&hist[receivers[e]], 1);
}

// ---------------- phase 1c: exclusive scan (single block, 1024 thr) ------
__global__ __launch_bounds__(1024) void scan_kernel(const int* __restrict__ hist,
                                                    int* __restrict__ offs) {
    __shared__ int part[1024];
    const int CHUNK = 20;  // 1024*20 = 20480 >= NN
    int t = threadIdx.x;
    int base = t * CHUNK;
    int local[CHUNK];
    int s = 0;
#pragma unroll
    for (int k = 0; k < CHUNK; k++) {
        int i = base + k;
        int v = (i < NN) ? hist[i] : 0;
        local[k] = s;
        s += v;
    }
    part[t] = s;
    __syncthreads();
    for (int off = 1; off < 1024; off <<= 1) {
        int v = 0;
        if (t >= off) v = part[t - off];
        __syncthreads();
        if (t >= off) part[t] += v;
        __syncthreads();
    }
    int pre = (t > 0) ? part[t - 1] : 0;
#pragma unroll
    for (int k = 0; k < CHUNK; k++) {
        int i = base + k;
        if (i < NN) offs[i] = pre + local[k];
    }
    if (t == 0) offs[NN] = E_EDGES;
}

// ---------------- phase 1d: scatter edges into receiver-sorted order -----
__global__ void scatter_kernel(const float* __restrict__ edges,
                               const int* __restrict__ senders,
                               const int* __restrict__ receivers,
                               const int* __restrict__ offs,
                               int* __restrict__ cursor,
                               float4* __restrict__ sorted) {
    int e = blockIdx.x * blockDim.x + threadIdx.x;
    if (e >= E_EDGES) return;
    int rc = receivers[e];
    int pos = offs[rc] + atomicAdd(&cursor[rc], 1);
    float4 rec;
    rec.x = edges[3 * e + 0];
    rec.y = edges[3 * e + 1];
    rec.z = edges[3 * e + 2];
    rec.w = __int_as_float(senders[e]);
    sorted[pos] = rec;
}

// ---------------- phase 2: per-(node,channel) gather, no atomics ---------
__global__ __launch_bounds__(256) void gather_kernel(
    const float4* __restrict__ sorted,
    const int*    __restrict__ offs,
    const float*  __restrict__ nodes0,
    const float*  __restrict__ nodes1,
    const float*  __restrict__ c00, const float* __restrict__ c01,
    const float*  __restrict__ c10, const float* __restrict__ c11,
    const float*  __restrict__ w000, const float* __restrict__ w011,
    const float*  __restrict__ w101, const float* __restrict__ w110,
    const float*  __restrict__ w111,
    float* __restrict__ out0,   // [NN, 32]
    float* __restrict__ out1)   // [NN, 48, 3]
{
    int tid  = blockIdx.x * blockDim.x + threadIdx.x;
    int node = tid >> 4;
    int c    = tid & 15;
    if (node >= NN) return;

    // per-channel constants into registers (loop-invariant)
    float k00[5], k01[5], k10[5], k11[5];
#pragma unroll
    for (int b = 0; b < 5; b++) {
        k00[b] = c00[c * 5 + b];
        k01[b] = c01[c * 5 + b];
        k10[b] = c10[c * 5 + b];
        k11[b] = c11[c * 5 + b];
    }

    int start = offs[node];
    int end   = offs[node + 1];

    // accumulators (weights & constant factors applied post-loop)
    float a000 = 0.f, a110 = 0.f;
    float a011x = 0.f, a011y = 0.f, a011z = 0.f;
    float a101x = 0.f, a101y = 0.f, a101z = 0.f;
    float a111x = 0.f, a111y = 0.f, a111z = 0.f;

    for (int i = start; i < end; i++) {
        float4 rec = sorted[i];
        int s = __float_as_int(rec.w);
        float r = sqrtf(rec.x * rec.x + rec.y * rec.y + rec.z * rec.z);
        float rbf[5];
#pragma unroll
        for (int b = 0; b < 5; b++) {
            float d = r - 0.875f * (float)b;
            rbf[b] = __expf(-0.7f * d * d);
        }
        float rad00 = 0.f, rad01 = 0.f, rad10 = 0.f, rad11 = 0.f;
#pragma unroll
        for (int b = 0; b < 5; b++) {
            rad00 = fmaf(rbf[b], k00[b], rad00);
            rad01 = fmaf(rbf[b], k01[b], rad01);
            rad10 = fmaf(rbf[b], k10[b], rad10);
            rad11 = fmaf(rbf[b], k11[b], rad11);
        }
        const float* n0p = nodes0 + s * NC;
        const float* n1p = nodes1 + (s * NC + c) * 3;
        float n0  = n0p[c];
        float n1a = n1p[0];
        float n1b = n1p[1];
        float n1c = n1p[2];

        // direction, real-basis order (y, z, x)
        float py = rec.y, pz = rec.z, px = rec.x;

        a000 = fmaf(n0, rad00, a000);
        a110 = fmaf(rad11, n1a * py + n1b * pz + n1c * px, a110);

        float kA = n0 * rad01;
        a011x = fmaf(kA, py, a011x);
        a011y = fmaf(kA, pz, a011y);
        a011z = fmaf(kA, px, a011z);

        a101x = fmaf(rad10, n1a, a101x);
        a101y = fmaf(rad10, n1b, a101y);
        a101z = fmaf(rad10, n1c, a101z);

        a111x = fmaf(rad11, n1b * px - n1c * pz, a111x);
        a111y = fmaf(rad11, n1c * py - n1a * px, a111y);
        a111z = fmaf(rad11, n1a * pz - n1b * py, a111z);
    }

    float s000 = w000[c] * Y00F;
    float s110 = w110[c] * RS3 * Y1CF;
    float s011 = w011[c] * Y1CF;
    float s101 = w101[c] * Y00F;
    float s111 = w111[c] * RS2 * Y1CF;

    out0[node * 32 + c]      = s000 * a000;
    out0[node * 32 + 16 + c] = s110 * a110;

    float* o1 = out1 + node * 144;
    o1[3 * c + 0] = s011 * a011x;
    o1[3 * c + 1] = s011 * a011y;
    o1[3 * c + 2] = s011 * a011z;
    o1[3 * (16 + c) + 0] = s101 * a101x;
    o1[3 * (16 + c) + 1] = s101 * a101y;
    o1[3 * (16 + c) + 2] = s101 * a101z;
    o1[3 * (32 + c) + 0] = s111 * a111x;
    o1[3 * (32 + c) + 1] = s111 * a111y;
    o1[3 * (32 + c) + 2] = s111 * a111z;
}

// ================= fallback (atomic) path, used only if ws too small =====
__global__ void init_out_fb(const float* __restrict__ coords,
                            float* __restrict__ out, int out_size) {
    int i = blockIdx.x * blockDim.x + threadIdx.x;
    if (i < 3 * NN) out[i] = coords[i];
    else if (i < out_size) out[i] = 0.0f;
}

__global__ __launch_bounds__(256) void tp_edges_fb(
    const float* __restrict__ edges, const int* __restrict__ senders,
    const int* __restrict__ receivers, const float* __restrict__ nodes0,
    const float* __restrict__ nodes1,
    const float* __restrict__ c00, const float* __restrict__ c01,
    const float* __restrict__ c10, const float* __restrict__ c11,
    const float* __restrict__ w000, const float* __restrict__ w011,
    const float* __restrict__ w101, const float* __restrict__ w110,
    const float* __restrict__ w111,
    float* __restrict__ out0, float* __restrict__ out1) {
    int e = blockIdx.x * blockDim.x + threadIdx.x;
    if (e >= E_EDGES) return;
    float ex = edges[3 * e + 0], ey = edges[3 * e + 1], ez = edges[3 * e + 2];
    float r = sqrtf(ex * ex + ey * ey + ez * ez);
    float rbf[5];
#pragma unroll
    for (int b = 0; b < 5; b++) {
        float d = r - 0.875f * (float)b;
        rbf[b] = __expf(-0.7f * d * d);
    }
    int s = senders[e], rc = receivers[e];
    const float* n0p = nodes0 + s * NC;
    const float* n1p = nodes1 + s * NC * 3;
    float* o0 = out0 + rc * 32;
    float* o1 = out1 + rc * 144;
    float pey = Y1CF * ey, pez = Y1CF * ez, pex = Y1CF * ex;
    for (int c = 0; c < NC; c++) {
        float rad00 = 0.f, rad01 = 0.f, rad10 = 0.f, rad11 = 0.f;
#pragma unroll
        for (int b = 0; b < 5; b++) {
            rad00 = fmaf(rbf[b], c00[c * 5 + b], rad00);
            rad01 = fmaf(rbf[b], c01[c * 5 + b], rad01);
            rad10 = fmaf(rbf[b], c10[c * 5 + b], rad10);
            rad11 = fmaf(rbf[b], c11[c * 5 + b], rad11);
        }
        float n0 = n0p[c];
        float n1a = n1p[3 * c + 0], n1b = n1p[3 * c + 1], n1c = n1p[3 * c + 2];
        float f11a = rad11 * pey, f11b = rad11 * pez, f11c = rad11 * pex;
        atomicAdd(&o0[c], w000[c] * n0 * rad00 * Y00F);
        atomicAdd(&o0[16 + c], w110[c] * RS3 * (n1a * f11a + n1b * f11b + n1c * f11c));
        float kA = w011[c] * n0 * rad01;
        atomicAdd(&o1[3 * c + 0], kA * pey);
        atomicAdd(&o1[3 * c + 1], kA * pez);
        atomicAdd(&o1[3 * c + 2], kA * pex);
        float kB = w101[c] * rad10 * Y00F;
        atomicAdd(&o1[3 * (16 + c) + 0], kB * n1a);
        atomicAdd(&o1[3 * (16 + c) + 1], kB * n1b);
        atomicAdd(&o1[3 * (16 + c) + 2], kB * n1c);
        float kC = w111[c] * RS2;
        atomicAdd(&o1[3 * (32 + c) + 0], kC * (n1b * f11c - n1c * f11b));
        atomicAdd(&o1[3 * (32 + c) + 1], kC * (n1c * f11a - n1a * f11c));
        atomicAdd(&o1[3 * (32 + c) + 2], kC * (n1a * f11b - n1b * f11a));
    }
}

extern "C" void kernel_launch(void* const* d_in, const int* in_sizes, int n_in,
                              void* d_out, int out_size, void* d_ws, size_t ws_size,
                              hipStream_t stream) {
    const float* coords    = (const float*)d_in[0];
    const float* nodes0    = (const float*)d_in[1];
    const float* nodes1    = (const float*)d_in[2];
    const float* edges     = (const float*)d_in[3];
    const int*   senders   = (const int*)  d_in[4];
    const int*   receivers = (const int*)  d_in[5];
    const float* c00       = (const float*)d_in[6];
    const float* c01       = (const float*)d_in[7];
    const float* c10       = (const float*)d_in[8];
    const float* c11       = (const float*)d_in[9];
    const float* w000      = (const float*)d_in[10];
    const float* w011      = (const float*)d_in[11];
    const float* w101      = (const float*)d_in[12];
    const float* w110      = (const float*)d_in[13];
    const float* w111      = (const float*)d_in[14];

    float* out  = (float*)d_out;
    float* out0 = out + 3 * NN;
    float* out1 = out + 3 * NN + NN * 2 * NC;

    // workspace layout
    size_t sorted_bytes = (size_t)E_EDGES * 16;
    size_t need = sorted_bytes + (size_t)(3 * NN + 1) * 4;

    copy_coords<<<(3 * NN + 255) / 256, 256, 0, stream>>>(coords, out);

    if (ws_size >= need) {
        float4* sorted = (float4*)d_ws;
        int* offs   = (int*)((char*)d_ws + sorted_bytes);   // NN+1
        int* hist   = offs + (NN + 1);                      // NN
        int* cursor = hist + NN;                            // NN

        zero_ints<<<(2 * NN + 255) / 256, 256, 0, stream>>>(hist, 2 * NN);
        hist_kernel<<<(E_EDGES + 255) / 256, 256, 0, stream>>>(receivers, hist);
        scan_kernel<<<1, 1024, 0, stream>>>(hist, offs);
        scatter_kernel<<<(E_EDGES + 255) / 256, 256, 0, stream>>>(
            edges, senders, receivers, offs, cursor, sorted);
        int total = NN * NC;
        gather_kernel<<<(total + 255) / 256, 256, 0, stream>>>(
            sorted, offs, nodes0, nodes1,
            c00, c01, c10, c11, w000, w011, w101, w110, w111, out0, out1);
    } else {
        init_out_fb<<<(out_size + 255) / 256, 256, 0, stream>>>(coords, out, out_size);
        tp_edges_fb<<<(E_EDGES + 255) / 256, 256, 0, stream>>>(
            edges, senders, receivers, nodes0, nodes1,
            c00, c01, c10, c11, w000, w011, w101, w110, w111, out0, out1);
    }
}

// Round 4
// 231.981 us; speedup vs baseline: 24.6363x; 1.0261x over previous
//
#include <hip/hip_runtime.h>

#define E_EDGES 640000
#define NN 20000
#define NC 16

#define Y00F 0.28209479177387814f
#define Y1CF 0.4886025119029199f
#define RS3  0.5773502691896258f
#define RS2  0.7071067811865476f

// native vector type usable with __builtin_nontemporal_*
typedef float nf4 __attribute__((ext_vector_type(4)));

// ---- init: coords passthrough + zero hist ----
__global__ void init_kernel(const float* __restrict__ coords,
                            float* __restrict__ out,
                            int* __restrict__ hist) {
    int i = blockIdx.x * blockDim.x + threadIdx.x;
    if (i < 3 * NN) out[i] = coords[i];
    if (i < NN) hist[i] = 0;
}

// ---- receiver histogram, 4 edges/thread ----
__global__ void hist_kernel(const int* __restrict__ receivers,
                            int* __restrict__ hist) {
    int t = blockIdx.x * blockDim.x + threadIdx.x;
    if (t >= E_EDGES / 4) return;
    int4 r = *(const int4*)(receivers + 4 * t);
    atomicAdd(&hist[r.x], 1);
    atomicAdd(&hist[r.y], 1);
    atomicAdd(&hist[r.z], 1);
    atomicAdd(&hist[r.w], 1);
}

// ---- scan stage 1: 20 blocks x 1024, coalesced chunk scan ----
__global__ __launch_bounds__(1024) void scan1_kernel(const int* __restrict__ hist,
                                                     int* __restrict__ offs,
                                                     int* __restrict__ btot) {
    __shared__ int sh[1024];
    int t = threadIdx.x, b = blockIdx.x;
    int i = b * 1024 + t;
    int v = (i < NN) ? hist[i] : 0;
    sh[t] = v;
    __syncthreads();
    for (int off = 1; off < 1024; off <<= 1) {
        int x = (t >= off) ? sh[t - off] : 0;
        __syncthreads();
        sh[t] += x;
        __syncthreads();
    }
    int incl = sh[t];
    if (i < NN) offs[i] = incl - v;  // exclusive within chunk
    if (t == 1023) btot[b] = incl;
}

// ---- scan stage 2: add chunk prefixes, init cursor = offs ----
__global__ __launch_bounds__(1024) void scan2_kernel(int* __restrict__ offs,
                                                     int* __restrict__ cursor,
                                                     const int* __restrict__ btot,
                                                     int nblk) {
    __shared__ int pre[64];
    int t = threadIdx.x, b = blockIdx.x;
    if (t == 0) {
        int s = 0;
        for (int k = 0; k < nblk; k++) { pre[k] = s; s += btot[k]; }
    }
    __syncthreads();
    int i = b * 1024 + t;
    if (i < NN) {
        int o = offs[i] + pre[b];
        offs[i] = o;
        cursor[i] = o;
    }
    if (b == 0 && t == 0) offs[NN] = E_EDGES;
}

// ---- scatter edges into receiver-sorted records, 4 edges/thread ----
__global__ void scatter_kernel(const float* __restrict__ edges,
                               const int* __restrict__ senders,
                               const int* __restrict__ receivers,
                               int* __restrict__ cursor,
                               nf4* __restrict__ sorted) {
    int t = blockIdx.x * blockDim.x + threadIdx.x;
    if (t >= E_EDGES / 4) return;
    int base = 4 * t;
    const float4 A = *(const float4*)(edges + 3 * base);
    const float4 B = *(const float4*)(edges + 3 * base + 4);
    const float4 C = *(const float4*)(edges + 3 * base + 8);
    int4 sv = *(const int4*)(senders + base);
    int4 rv = *(const int4*)(receivers + base);

    nf4 r0 = {A.x, A.y, A.z, __int_as_float(sv.x)};
    nf4 r1 = {A.w, B.x, B.y, __int_as_float(sv.y)};
    nf4 r2 = {B.z, B.w, C.x, __int_as_float(sv.z)};
    nf4 r3 = {C.y, C.z, C.w, __int_as_float(sv.w)};

    int p0 = atomicAdd(&cursor[rv.x], 1);
    __builtin_nontemporal_store(r0, &sorted[p0]);
    int p1 = atomicAdd(&cursor[rv.y], 1);
    __builtin_nontemporal_store(r1, &sorted[p1]);
    int p2 = atomicAdd(&cursor[rv.z], 1);
    __builtin_nontemporal_store(r2, &sorted[p2]);
    int p3 = atomicAdd(&cursor[rv.w], 1);
    __builtin_nontemporal_store(r3, &sorted[p3]);
}

// ---- gather: per-(node,channel), no atomics ----
__global__ __launch_bounds__(256) void gather_kernel(
    const nf4*    __restrict__ sorted,
    const int*    __restrict__ offs,
    const float*  __restrict__ nodes0,
    const float*  __restrict__ nodes1,
    const float*  __restrict__ c00, const float* __restrict__ c01,
    const float*  __restrict__ c10, const float* __restrict__ c11,
    const float*  __restrict__ w000, const float* __restrict__ w011,
    const float*  __restrict__ w101, const float* __restrict__ w110,
    const float*  __restrict__ w111,
    float* __restrict__ out0,   // [NN, 32]
    float* __restrict__ out1)   // [NN, 48, 3]
{
    int tid  = blockIdx.x * blockDim.x + threadIdx.x;
    int node = tid >> 4;
    int c    = tid & 15;
    if (node >= NN) return;

    float k00[5], k01[5], k10[5], k11[5];
#pragma unroll
    for (int b = 0; b < 5; b++) {
        k00[b] = c00[c * 5 + b];
        k01[b] = c01[c * 5 + b];
        k10[b] = c10[c * 5 + b];
        k11[b] = c11[c * 5 + b];
    }

    int start = offs[node];
    int end   = offs[node + 1];

    float a000 = 0.f, a110 = 0.f;
    float a011x = 0.f, a011y = 0.f, a011z = 0.f;
    float a101x = 0.f, a101y = 0.f, a101z = 0.f;
    float a111x = 0.f, a111y = 0.f, a111z = 0.f;

#define BODY(rec)                                                          \
    {                                                                      \
        int s = __float_as_int(rec.w);                                     \
        float r = sqrtf(rec.x * rec.x + rec.y * rec.y + rec.z * rec.z);    \
        float rbf[5];                                                      \
        _Pragma("unroll") for (int b = 0; b < 5; b++) {                    \
            float d = r - 0.875f * (float)b;                               \
            rbf[b] = __expf(-0.7f * d * d);                                \
        }                                                                  \
        float rad00 = 0.f, rad01 = 0.f, rad10 = 0.f, rad11 = 0.f;          \
        _Pragma("unroll") for (int b = 0; b < 5; b++) {                    \
            rad00 = fmaf(rbf[b], k00[b], rad00);                           \
            rad01 = fmaf(rbf[b], k01[b], rad01);                           \
            rad10 = fmaf(rbf[b], k10[b], rad10);                           \
            rad11 = fmaf(rbf[b], k11[b], rad11);                           \
        }                                                                  \
        float n0  = nodes0[s * NC + c];                                    \
        const float* n1p = nodes1 + (s * NC + c) * 3;                      \
        float n1a = n1p[0], n1b = n1p[1], n1c = n1p[2];                    \
        float py = rec.y, pz = rec.z, px = rec.x;                          \
        a000 = fmaf(n0, rad00, a000);                                      \
        a110 = fmaf(rad11, n1a * py + n1b * pz + n1c * px, a110);          \
        float kA = n0 * rad01;                                             \
        a011x = fmaf(kA, py, a011x);                                       \
        a011y = fmaf(kA, pz, a011y);                                       \
        a011z = fmaf(kA, px, a011z);                                       \
        a101x = fmaf(rad10, n1a, a101x);                                   \
        a101y = fmaf(rad10, n1b, a101y);                                   \
        a101z = fmaf(rad10, n1c, a101z);                                   \
        a111x = fmaf(rad11, n1b * px - n1c * pz, a111x);                   \
        a111y = fmaf(rad11, n1c * py - n1a * px, a111y);                   \
        a111z = fmaf(rad11, n1a * pz - n1b * py, a111z);                   \
    }

    int i = start;
    for (; i + 1 < end; i += 2) {
        nf4 r0 = __builtin_nontemporal_load(&sorted[i]);
        nf4 r1 = __builtin_nontemporal_load(&sorted[i + 1]);
        BODY(r0);
        BODY(r1);
    }
    if (i < end) {
        nf4 r0 = __builtin_nontemporal_load(&sorted[i]);
        BODY(r0);
    }
#undef BODY

    float s000 = w000[c] * Y00F;
    float s110 = w110[c] * RS3 * Y1CF;
    float s011 = w011[c] * Y1CF;
    float s101 = w101[c] * Y00F;
    float s111 = w111[c] * RS2 * Y1CF;

    out0[node * 32 + c]      = s000 * a000;
    out0[node * 32 + 16 + c] = s110 * a110;

    float* o1 = out1 + node * 144;
    o1[3 * c + 0] = s011 * a011x;
    o1[3 * c + 1] = s011 * a011y;
    o1[3 * c + 2] = s011 * a011z;
    o1[3 * (16 + c) + 0] = s101 * a101x;
    o1[3 * (16 + c) + 1] = s101 * a101y;
    o1[3 * (16 + c) + 2] = s101 * a101z;
    o1[3 * (32 + c) + 0] = s111 * a111x;
    o1[3 * (32 + c) + 1] = s111 * a111y;
    o1[3 * (32 + c) + 2] = s111 * a111z;
}

// ================= fallback (atomic) path, used only if ws too small =====
__global__ void init_out_fb(const float* __restrict__ coords,
                            float* __restrict__ out, int out_size) {
    int i = blockIdx.x * blockDim.x + threadIdx.x;
    if (i < 3 * NN) out[i] = coords[i];
    else if (i < out_size) out[i] = 0.0f;
}

__global__ __launch_bounds__(256) void tp_edges_fb(
    const float* __restrict__ edges, const int* __restrict__ senders,
    const int* __restrict__ receivers, const float* __restrict__ nodes0,
    const float* __restrict__ nodes1,
    const float* __restrict__ c00, const float* __restrict__ c01,
    const float* __restrict__ c10, const float* __restrict__ c11,
    const float* __restrict__ w000, const float* __restrict__ w011,
    const float* __restrict__ w101, const float* __restrict__ w110,
    const float* __restrict__ w111,
    float* __restrict__ out0, float* __restrict__ out1) {
    int e = blockIdx.x * blockDim.x + threadIdx.x;
    if (e >= E_EDGES) return;
    float ex = edges[3 * e + 0], ey = edges[3 * e + 1], ez = edges[3 * e + 2];
    float r = sqrtf(ex * ex + ey * ey + ez * ez);
    float rbf[5];
#pragma unroll
    for (int b = 0; b < 5; b++) {
        float d = r - 0.875f * (float)b;
        rbf[b] = __expf(-0.7f * d * d);
    }
    int s = senders[e], rc = receivers[e];
    const float* n0p = nodes0 + s * NC;
    const float* n1p = nodes1 + s * NC * 3;
    float* o0 = out0 + rc * 32;
    float* o1 = out1 + rc * 144;
    float pey = Y1CF * ey, pez = Y1CF * ez, pex = Y1CF * ex;
    for (int c = 0; c < NC; c++) {
        float rad00 = 0.f, rad01 = 0.f, rad10 = 0.f, rad11 = 0.f;
#pragma unroll
        for (int b = 0; b < 5; b++) {
            rad00 = fmaf(rbf[b], c00[c * 5 + b], rad00);
            rad01 = fmaf(rbf[b], c01[c * 5 + b], rad01);
            rad10 = fmaf(rbf[b], c10[c * 5 + b], rad10);
            rad11 = fmaf(rbf[b], c11[c * 5 + b], rad11);
        }
        float n0 = n0p[c];
        float n1a = n1p[3 * c + 0], n1b = n1p[3 * c + 1], n1c = n1p[3 * c + 2];
        float f11a = rad11 * pey, f11b = rad11 * pez, f11c = rad11 * pex;
        atomicAdd(&o0[c], w000[c] * n0 * rad00 * Y00F);
        atomicAdd(&o0[16 + c], w110[c] * RS3 * (n1a * f11a + n1b * f11b + n1c * f11c));
        float kA = w011[c] * n0 * rad01;
        atomicAdd(&o1[3 * c + 0], kA * pey);
        atomicAdd(&o1[3 * c + 1], kA * pez);
        atomicAdd(&o1[3 * c + 2], kA * pex);
        float kB = w101[c] * rad10 * Y00F;
        atomicAdd(&o1[3 * (16 + c) + 0], kB * n1a);
        atomicAdd(&o1[3 * (16 + c) + 1], kB * n1b);
        atomicAdd(&o1[3 * (16 + c) + 2], kB * n1c);
        float kC = w111[c] * RS2;
        atomicAdd(&o1[3 * (32 + c) + 0], kC * (n1b * f11c - n1c * f11b));
        atomicAdd(&o1[3 * (32 + c) + 1], kC * (n1c * f11a - n1a * f11c));
        atomicAdd(&o1[3 * (32 + c) + 2], kC * (n1a * f11b - n1b * f11a));
    }
}

extern "C" void kernel_launch(void* const* d_in, const int* in_sizes, int n_in,
                              void* d_out, int out_size, void* d_ws, size_t ws_size,
                              hipStream_t stream) {
    const float* coords    = (const float*)d_in[0];
    const float* nodes0    = (const float*)d_in[1];
    const float* nodes1    = (const float*)d_in[2];
    const float* edges     = (const float*)d_in[3];
    const int*   senders   = (const int*)  d_in[4];
    const int*   receivers = (const int*)  d_in[5];
    const float* c00       = (const float*)d_in[6];
    const float* c01       = (const float*)d_in[7];
    const float* c10       = (const float*)d_in[8];
    const float* c11       = (const float*)d_in[9];
    const float* w000      = (const float*)d_in[10];
    const float* w011      = (const float*)d_in[11];
    const float* w101      = (const float*)d_in[12];
    const float* w110      = (const float*)d_in[13];
    const float* w111      = (const float*)d_in[14];

    float* out  = (float*)d_out;
    float* out0 = out + 3 * NN;
    float* out1 = out + 3 * NN + NN * 2 * NC;

    size_t sorted_bytes = (size_t)E_EDGES * 16;
    size_t need = sorted_bytes + (size_t)(3 * NN + 1 + 64) * 4;

    if (ws_size >= need) {
        nf4* sorted = (nf4*)d_ws;
        int* offs   = (int*)((char*)d_ws + sorted_bytes);   // NN+1
        int* cursor = offs + (NN + 1);                      // NN
        int* hist   = cursor + NN;                          // NN
        int* btot   = hist + NN;                            // <=64

        const int NBLK = (NN + 1023) / 1024;  // 20

        init_kernel<<<(3 * NN + 255) / 256, 256, 0, stream>>>(coords, out, hist);
        hist_kernel<<<(E_EDGES / 4 + 255) / 256, 256, 0, stream>>>(receivers, hist);
        scan1_kernel<<<NBLK, 1024, 0, stream>>>(hist, offs, btot);
        scan2_kernel<<<NBLK, 1024, 0, stream>>>(offs, cursor, btot, NBLK);
        scatter_kernel<<<(E_EDGES / 4 + 255) / 256, 256, 0, stream>>>(
            edges, senders, receivers, cursor, sorted);
        gather_kernel<<<(NN * NC + 255) / 256, 256, 0, stream>>>(
            sorted, offs, nodes0, nodes1,
            c00, c01, c10, c11, w000, w011, w101, w110, w111, out0, out1);
    } else {
        init_out_fb<<<(out_size + 255) / 256, 256, 0, stream>>>(coords, out, out_size);
        tp_edges_fb<<<(E_EDGES + 255) / 256, 256, 0, stream>>>(
            edges, senders, receivers, nodes0, nodes1,
            c00, c01, c10, c11, w000, w011, w101, w110, w111, out0, out1);
    }
}

// Round 5
// 217.907 us; speedup vs baseline: 26.2276x; 1.0646x over previous
//
#include <hip/hip_runtime.h>

#define E_EDGES 640000
#define NN 20000
#define NC 16

#define Y00F 0.28209479177387814f
#define Y1CF 0.4886025119029199f
#define RS3  0.5773502691896258f
#define RS2  0.7071067811865476f

// native vector type usable with __builtin_nontemporal_*
typedef float nf4 __attribute__((ext_vector_type(4)));

// ---- init: coords passthrough + zero hist ----
__global__ void init_kernel(const float* __restrict__ coords,
                            float* __restrict__ out,
                            int* __restrict__ hist) {
    int i = blockIdx.x * blockDim.x + threadIdx.x;
    if (i < 3 * NN) out[i] = coords[i];
    if (i < NN) hist[i] = 0;
}

// ---- receiver histogram, 4 edges/thread ----
__global__ void hist_kernel(const int* __restrict__ receivers,
                            int* __restrict__ hist) {
    int t = blockIdx.x * blockDim.x + threadIdx.x;
    if (t >= E_EDGES / 4) return;
    int4 r = *(const int4*)(receivers + 4 * t);
    atomicAdd(&hist[r.x], 1);
    atomicAdd(&hist[r.y], 1);
    atomicAdd(&hist[r.z], 1);
    atomicAdd(&hist[r.w], 1);
}

// ---- scan stage 1: 20 blocks x 1024, coalesced chunk scan ----
__global__ __launch_bounds__(1024) void scan1_kernel(const int* __restrict__ hist,
                                                     int* __restrict__ offs,
                                                     int* __restrict__ btot) {
    __shared__ int sh[1024];
    int t = threadIdx.x, b = blockIdx.x;
    int i = b * 1024 + t;
    int v = (i < NN) ? hist[i] : 0;
    sh[t] = v;
    __syncthreads();
    for (int off = 1; off < 1024; off <<= 1) {
        int x = (t >= off) ? sh[t - off] : 0;
        __syncthreads();
        sh[t] += x;
        __syncthreads();
    }
    int incl = sh[t];
    if (i < NN) offs[i] = incl - v;  // exclusive within chunk
    if (t == 1023) btot[b] = incl;
}

// ---- scan stage 2: add chunk prefixes, init cursor = offs ----
__global__ __launch_bounds__(1024) void scan2_kernel(int* __restrict__ offs,
                                                     int* __restrict__ cursor,
                                                     const int* __restrict__ btot,
                                                     int nblk) {
    __shared__ int pre[64];
    int t = threadIdx.x, b = blockIdx.x;
    if (t == 0) {
        int s = 0;
        for (int k = 0; k < nblk; k++) { pre[k] = s; s += btot[k]; }
    }
    __syncthreads();
    int i = b * 1024 + t;
    if (i < NN) {
        int o = offs[i] + pre[b];
        offs[i] = o;
        cursor[i] = o;
    }
    if (b == 0 && t == 0) offs[NN] = E_EDGES;
}

// ---- scatter edges into receiver-sorted records, 1 edge/thread ----
// Regular (writeback) stores: L2 merges the 4 records per 64B line.
__global__ void scatter_kernel(const float* __restrict__ edges,
                               const int* __restrict__ senders,
                               const int* __restrict__ receivers,
                               int* __restrict__ cursor,
                               nf4* __restrict__ sorted) {
    int e = blockIdx.x * blockDim.x + threadIdx.x;
    if (e >= E_EDGES) return;
    float ex = edges[3 * e + 0];
    float ey = edges[3 * e + 1];
    float ez = edges[3 * e + 2];
    int s  = senders[e];
    int rc = receivers[e];
    int pos = atomicAdd(&cursor[rc], 1);
    nf4 rec = {ex, ey, ez, __int_as_float(s)};
    sorted[pos] = rec;
}

// ---- gather: one wave per node, lane = c + 16*j, shfl-reduce over j ----
__global__ __launch_bounds__(256) void gather_kernel(
    const nf4*    __restrict__ sorted,
    const int*    __restrict__ offs,
    const float*  __restrict__ nodes0,
    const float*  __restrict__ nodes1,
    const float*  __restrict__ c00, const float* __restrict__ c01,
    const float*  __restrict__ c10, const float* __restrict__ c11,
    const float*  __restrict__ w000, const float* __restrict__ w011,
    const float*  __restrict__ w101, const float* __restrict__ w110,
    const float*  __restrict__ w111,
    float* __restrict__ out0,   // [NN, 32]
    float* __restrict__ out1)   // [NN, 48, 3]
{
    int gtid = blockIdx.x * blockDim.x + threadIdx.x;
    int node = gtid >> 6;          // one wave64 per node
    int lane = threadIdx.x & 63;
    int c    = lane & 15;
    int j    = lane >> 4;          // 0..3 edge-parallel slots
    if (node >= NN) return;

    float k00[5], k01[5], k10[5], k11[5];
#pragma unroll
    for (int b = 0; b < 5; b++) {
        k00[b] = c00[c * 5 + b];
        k01[b] = c01[c * 5 + b];
        k10[b] = c10[c * 5 + b];
        k11[b] = c11[c * 5 + b];
    }

    int start = offs[node];
    int end   = offs[node + 1];

    float a000 = 0.f, a110 = 0.f;
    float a011x = 0.f, a011y = 0.f, a011z = 0.f;
    float a101x = 0.f, a101y = 0.f, a101z = 0.f;
    float a111x = 0.f, a111y = 0.f, a111z = 0.f;

#define BODY(rec)                                                          \
    {                                                                      \
        int s = __float_as_int(rec.w);                                     \
        float r = sqrtf(rec.x * rec.x + rec.y * rec.y + rec.z * rec.z);    \
        float rbf[5];                                                      \
        _Pragma("unroll") for (int b = 0; b < 5; b++) {                    \
            float d = r - 0.875f * (float)b;                               \
            rbf[b] = __expf(-0.7f * d * d);                                \
        }                                                                  \
        float rad00 = 0.f, rad01 = 0.f, rad10 = 0.f, rad11 = 0.f;          \
        _Pragma("unroll") for (int b = 0; b < 5; b++) {                    \
            rad00 = fmaf(rbf[b], k00[b], rad00);                           \
            rad01 = fmaf(rbf[b], k01[b], rad01);                           \
            rad10 = fmaf(rbf[b], k10[b], rad10);                           \
            rad11 = fmaf(rbf[b], k11[b], rad11);                           \
        }                                                                  \
        float n0  = nodes0[s * NC + c];                                    \
        const float* n1p = nodes1 + (s * NC + c) * 3;                      \
        float n1a = n1p[0], n1b = n1p[1], n1c = n1p[2];                    \
        float py = rec.y, pz = rec.z, px = rec.x;                          \
        a000 = fmaf(n0, rad00, a000);                                      \
        a110 = fmaf(rad11, n1a * py + n1b * pz + n1c * px, a110);          \
        float kA = n0 * rad01;                                             \
        a011x = fmaf(kA, py, a011x);                                       \
        a011y = fmaf(kA, pz, a011y);                                       \
        a011z = fmaf(kA, px, a011z);                                       \
        a101x = fmaf(rad10, n1a, a101x);                                   \
        a101y = fmaf(rad10, n1b, a101y);                                   \
        a101z = fmaf(rad10, n1c, a101z);                                   \
        a111x = fmaf(rad11, n1b * px - n1c * pz, a111x);                   \
        a111y = fmaf(rad11, n1c * py - n1a * px, a111y);                   \
        a111z = fmaf(rad11, n1a * pz - n1b * py, a111z);                   \
    }

    int i = start + j;
    for (; i + 4 < end; i += 8) {
        nf4 r0 = __builtin_nontemporal_load(&sorted[i]);
        nf4 r1 = __builtin_nontemporal_load(&sorted[i + 4]);
        BODY(r0);
        BODY(r1);
    }
    if (i < end) {
        nf4 r0 = __builtin_nontemporal_load(&sorted[i]);
        BODY(r0);
    }
#undef BODY

    // reduce the 4 j-slots (lane bits 4 and 5)
#define RED(v) v += __shfl_xor(v, 16, 64); v += __shfl_xor(v, 32, 64)
    RED(a000); RED(a110);
    RED(a011x); RED(a011y); RED(a011z);
    RED(a101x); RED(a101y); RED(a101z);
    RED(a111x); RED(a111y); RED(a111z);
#undef RED

    if (j == 0) {
        float s000 = w000[c] * Y00F;
        float s110 = w110[c] * RS3 * Y1CF;
        float s011 = w011[c] * Y1CF;
        float s101 = w101[c] * Y00F;
        float s111 = w111[c] * RS2 * Y1CF;

        out0[node * 32 + c]      = s000 * a000;
        out0[node * 32 + 16 + c] = s110 * a110;

        float* o1 = out1 + node * 144;
        o1[3 * c + 0] = s011 * a011x;
        o1[3 * c + 1] = s011 * a011y;
        o1[3 * c + 2] = s011 * a011z;
        o1[3 * (16 + c) + 0] = s101 * a101x;
        o1[3 * (16 + c) + 1] = s101 * a101y;
        o1[3 * (16 + c) + 2] = s101 * a101z;
        o1[3 * (32 + c) + 0] = s111 * a111x;
        o1[3 * (32 + c) + 1] = s111 * a111y;
        o1[3 * (32 + c) + 2] = s111 * a111z;
    }
}

// ================= fallback (atomic) path, used only if ws too small =====
__global__ void init_out_fb(const float* __restrict__ coords,
                            float* __restrict__ out, int out_size) {
    int i = blockIdx.x * blockDim.x + threadIdx.x;
    if (i < 3 * NN) out[i] = coords[i];
    else if (i < out_size) out[i] = 0.0f;
}

__global__ __launch_bounds__(256) void tp_edges_fb(
    const float* __restrict__ edges, const int* __restrict__ senders,
    const int* __restrict__ receivers, const float* __restrict__ nodes0,
    const float* __restrict__ nodes1,
    const float* __restrict__ c00, const float* __restrict__ c01,
    const float* __restrict__ c10, const float* __restrict__ c11,
    const float* __restrict__ w000, const float* __restrict__ w011,
    const float* __restrict__ w101, const float* __restrict__ w110,
    const float* __restrict__ w111,
    float* __restrict__ out0, float* __restrict__ out1) {
    int e = blockIdx.x * blockDim.x + threadIdx.x;
    if (e >= E_EDGES) return;
    float ex = edges[3 * e + 0], ey = edges[3 * e + 1], ez = edges[3 * e + 2];
    float r = sqrtf(ex * ex + ey * ey + ez * ez);
    float rbf[5];
#pragma unroll
    for (int b = 0; b < 5; b++) {
        float d = r - 0.875f * (float)b;
        rbf[b] = __expf(-0.7f * d * d);
    }
    int s = senders[e], rc = receivers[e];
    const float* n0p = nodes0 + s * NC;
    const float* n1p = nodes1 + s * NC * 3;
    float* o0 = out0 + rc * 32;
    float* o1 = out1 + rc * 144;
    float pey = Y1CF * ey, pez = Y1CF * ez, pex = Y1CF * ex;
    for (int c = 0; c < NC; c++) {
        float rad00 = 0.f, rad01 = 0.f, rad10 = 0.f, rad11 = 0.f;
#pragma unroll
        for (int b = 0; b < 5; b++) {
            rad00 = fmaf(rbf[b], c00[c * 5 + b], rad00);
            rad01 = fmaf(rbf[b], c01[c * 5 + b], rad01);
            rad10 = fmaf(rbf[b], c10[c * 5 + b], rad10);
            rad11 = fmaf(rbf[b], c11[c * 5 + b], rad11);
        }
        float n0 = n0p[c];
        float n1a = n1p[3 * c + 0], n1b = n1p[3 * c + 1], n1c = n1p[3 * c + 2];
        float f11a = rad11 * pey, f11b = rad11 * pez, f11c = rad11 * pex;
        atomicAdd(&o0[c], w000[c] * n0 * rad00 * Y00F);
        atomicAdd(&o0[16 + c], w110[c] * RS3 * (n1a * f11a + n1b * f11b + n1c * f11c));
        float kA = w011[c] * n0 * rad01;
        atomicAdd(&o1[3 * c + 0], kA * pey);
        atomicAdd(&o1[3 * c + 1], kA * pez);
        atomicAdd(&o1[3 * c + 2], kA * pex);
        float kB = w101[c] * rad10 * Y00F;
        atomicAdd(&o1[3 * (16 + c) + 0], kB * n1a);
        atomicAdd(&o1[3 * (16 + c) + 1], kB * n1b);
        atomicAdd(&o1[3 * (16 + c) + 2], kB * n1c);
        float kC = w111[c] * RS2;
        atomicAdd(&o1[3 * (32 + c) + 0], kC * (n1b * f11c - n1c * f11b));
        atomicAdd(&o1[3 * (32 + c) + 1], kC * (n1c * f11a - n1a * f11c));
        atomicAdd(&o1[3 * (32 + c) + 2], kC * (n1a * f11b - n1b * f11a));
    }
}

extern "C" void kernel_launch(void* const* d_in, const int* in_sizes, int n_in,
                              void* d_out, int out_size, void* d_ws, size_t ws_size,
                              hipStream_t stream) {
    const float* coords    = (const float*)d_in[0];
    const float* nodes0    = (const float*)d_in[1];
    const float* nodes1    = (const float*)d_in[2];
    const float* edges     = (const float*)d_in[3];
    const int*   senders   = (const int*)  d_in[4];
    const int*   receivers = (const int*)  d_in[5];
    const float* c00       = (const float*)d_in[6];
    const float* c01       = (const float*)d_in[7];
    const float* c10       = (const float*)d_in[8];
    const float* c11       = (const float*)d_in[9];
    const float* w000      = (const float*)d_in[10];
    const float* w011      = (const float*)d_in[11];
    const float* w101      = (const float*)d_in[12];
    const float* w110      = (const float*)d_in[13];
    const float* w111      = (const float*)d_in[14];

    float* out  = (float*)d_out;
    float* out0 = out + 3 * NN;
    float* out1 = out + 3 * NN + NN * 2 * NC;

    size_t sorted_bytes = (size_t)E_EDGES * 16;
    size_t need = sorted_bytes + (size_t)(3 * NN + 1 + 64) * 4;

    if (ws_size >= need) {
        nf4* sorted = (nf4*)d_ws;
        int* offs   = (int*)((char*)d_ws + sorted_bytes);   // NN+1
        int* cursor = offs + (NN + 1);                      // NN
        int* hist   = cursor + NN;                          // NN
        int* btot   = hist + NN;                            // <=64

        const int NBLK = (NN + 1023) / 1024;  // 20

        init_kernel<<<(3 * NN + 255) / 256, 256, 0, stream>>>(coords, out, hist);
        hist_kernel<<<(E_EDGES / 4 + 255) / 256, 256, 0, stream>>>(receivers, hist);
        scan1_kernel<<<NBLK, 1024, 0, stream>>>(hist, offs, btot);
        scan2_kernel<<<NBLK, 1024, 0, stream>>>(offs, cursor, btot, NBLK);
        scatter_kernel<<<(E_EDGES + 255) / 256, 256, 0, stream>>>(
            edges, senders, receivers, cursor, sorted);
        gather_kernel<<<(NN * 64 + 255) / 256, 256, 0, stream>>>(
            sorted, offs, nodes0, nodes1,
            c00, c01, c10, c11, w000, w011, w101, w110, w111, out0, out1);
    } else {
        init_out_fb<<<(out_size + 255) / 256, 256, 0, stream>>>(coords, out, out_size);
        tp_edges_fb<<<(E_EDGES + 255) / 256, 256, 0, stream>>>(
            edges, senders, receivers, nodes0, nodes1,
            c00, c01, c10, c11, w000, w011, w101, w110, w111, out0, out1);
    }
}

// Round 6
// 171.176 us; speedup vs baseline: 33.3877x; 1.2730x over previous
//
#include <hip/hip_runtime.h>

#define E_EDGES 640000
#define NN 20000
#define NC 16
#define PBIN 64   // fixed bin capacity per node (Poisson(32) tail ~1e-7)

#define Y00F 0.28209479177387814f
#define Y1CF 0.4886025119029199f
#define RS3  0.5773502691896258f
#define RS2  0.7071067811865476f

typedef float nf4 __attribute__((ext_vector_type(4)));

// ======================= shared device math =======================
struct Acc {
    float a000, a110;
    float a011x, a011y, a011z;
    float a101x, a101y, a101z;
    float a111x, a111y, a111z;
};

__device__ __forceinline__ void edge_body(const nf4 rec,
                                          const float* __restrict__ nodes0,
                                          const float* __restrict__ nodes1,
                                          const float k00[5], const float k01[5],
                                          const float k10[5], const float k11[5],
                                          int c, Acc& A) {
    int s = __float_as_int(rec.w);
    float r = sqrtf(rec.x * rec.x + rec.y * rec.y + rec.z * rec.z);
    float rbf[5];
#pragma unroll
    for (int b = 0; b < 5; b++) {
        float d = r - 0.875f * (float)b;
        rbf[b] = __expf(-0.7f * d * d);
    }
    float rad00 = 0.f, rad01 = 0.f, rad10 = 0.f, rad11 = 0.f;
#pragma unroll
    for (int b = 0; b < 5; b++) {
        rad00 = fmaf(rbf[b], k00[b], rad00);
        rad01 = fmaf(rbf[b], k01[b], rad01);
        rad10 = fmaf(rbf[b], k10[b], rad10);
        rad11 = fmaf(rbf[b], k11[b], rad11);
    }
    float n0 = nodes0[s * NC + c];
    const float* n1p = nodes1 + (s * NC + c) * 3;
    float n1a = n1p[0], n1b = n1p[1], n1c = n1p[2];
    float py = rec.y, pz = rec.z, px = rec.x;
    A.a000 = fmaf(n0, rad00, A.a000);
    A.a110 = fmaf(rad11, n1a * py + n1b * pz + n1c * px, A.a110);
    float kA = n0 * rad01;
    A.a011x = fmaf(kA, py, A.a011x);
    A.a011y = fmaf(kA, pz, A.a011y);
    A.a011z = fmaf(kA, px, A.a011z);
    A.a101x = fmaf(rad10, n1a, A.a101x);
    A.a101y = fmaf(rad10, n1b, A.a101y);
    A.a101z = fmaf(rad10, n1c, A.a101z);
    A.a111x = fmaf(rad11, n1b * px - n1c * pz, A.a111x);
    A.a111y = fmaf(rad11, n1c * py - n1a * px, A.a111y);
    A.a111z = fmaf(rad11, n1a * pz - n1b * py, A.a111z);
}

// ======================= tier 1: direct binning =======================

// init: coords passthrough + zero cnt + zero overflow counter
__global__ void init1_kernel(const float* __restrict__ coords,
                             float* __restrict__ out,
                             int* __restrict__ cnt,
                             int* __restrict__ ovf_count) {
    int i = blockIdx.x * blockDim.x + threadIdx.x;
    if (i < 3 * NN) out[i] = coords[i];
    if (i < NN) cnt[i] = 0;
    if (i == 0) *ovf_count = 0;
}

// fused hist+scatter: one atomic pass, direct slot placement
__global__ void bin_kernel(const float* __restrict__ edges,
                           const int* __restrict__ senders,
                           const int* __restrict__ receivers,
                           int* __restrict__ cnt,
                           nf4* __restrict__ bins,
                           int* __restrict__ ovf_count,
                           int* __restrict__ ovf_list) {
    int e = blockIdx.x * blockDim.x + threadIdx.x;
    if (e >= E_EDGES) return;
    float ex = edges[3 * e + 0];
    float ey = edges[3 * e + 1];
    float ez = edges[3 * e + 2];
    int s  = senders[e];
    int rc = receivers[e];
    int pos = atomicAdd(&cnt[rc], 1);
    if (pos < PBIN) {
        nf4 rec = {ex, ey, ez, __int_as_float(s)};
        bins[rc * PBIN + pos] = rec;
    } else {
        int k = atomicAdd(ovf_count, 1);
        if (k < 4096) ovf_list[k] = e;
    }
}

// gather: one wave per node, lane = c + 16*j, shfl-reduce over j
__global__ __launch_bounds__(256) void gather1_kernel(
    const nf4*    __restrict__ bins,
    const int*    __restrict__ cnt,
    const float*  __restrict__ nodes0,
    const float*  __restrict__ nodes1,
    const float*  __restrict__ c00, const float* __restrict__ c01,
    const float*  __restrict__ c10, const float* __restrict__ c11,
    const float*  __restrict__ w000, const float* __restrict__ w011,
    const float*  __restrict__ w101, const float* __restrict__ w110,
    const float*  __restrict__ w111,
    float* __restrict__ out0, float* __restrict__ out1)
{
    int gtid = blockIdx.x * blockDim.x + threadIdx.x;
    int node = gtid >> 6;
    int lane = threadIdx.x & 63;
    int c    = lane & 15;
    int j    = lane >> 4;
    if (node >= NN) return;

    float k00[5], k01[5], k10[5], k11[5];
#pragma unroll
    for (int b = 0; b < 5; b++) {
        k00[b] = c00[c * 5 + b];
        k01[b] = c01[c * 5 + b];
        k10[b] = c10[c * 5 + b];
        k11[b] = c11[c * 5 + b];
    }

    int n = cnt[node];
    n = (n < PBIN) ? n : PBIN;
    const nf4* base = bins + node * PBIN;

    Acc A = {};
    int i = j;
    for (; i + 4 < n; i += 8) {
        nf4 r0 = __builtin_nontemporal_load(&base[i]);
        nf4 r1 = __builtin_nontemporal_load(&base[i + 4]);
        edge_body(r0, nodes0, nodes1, k00, k01, k10, k11, c, A);
        edge_body(r1, nodes0, nodes1, k00, k01, k10, k11, c, A);
    }
    if (i < n) {
        nf4 r0 = __builtin_nontemporal_load(&base[i]);
        edge_body(r0, nodes0, nodes1, k00, k01, k10, k11, c, A);
    }

#define RED(v) v += __shfl_xor(v, 16, 64); v += __shfl_xor(v, 32, 64)
    RED(A.a000); RED(A.a110);
    RED(A.a011x); RED(A.a011y); RED(A.a011z);
    RED(A.a101x); RED(A.a101y); RED(A.a101z);
    RED(A.a111x); RED(A.a111y); RED(A.a111z);
#undef RED

    if (j == 0) {
        float s000 = w000[c] * Y00F;
        float s110 = w110[c] * RS3 * Y1CF;
        float s011 = w011[c] * Y1CF;
        float s101 = w101[c] * Y00F;
        float s111 = w111[c] * RS2 * Y1CF;

        out0[node * 32 + c]      = s000 * A.a000;
        out0[node * 32 + 16 + c] = s110 * A.a110;

        float* o1 = out1 + node * 144;
        o1[3 * c + 0] = s011 * A.a011x;
        o1[3 * c + 1] = s011 * A.a011y;
        o1[3 * c + 2] = s011 * A.a011z;
        o1[3 * (16 + c) + 0] = s101 * A.a101x;
        o1[3 * (16 + c) + 1] = s101 * A.a101y;
        o1[3 * (16 + c) + 2] = s101 * A.a101z;
        o1[3 * (32 + c) + 0] = s111 * A.a111x;
        o1[3 * (32 + c) + 1] = s111 * A.a111y;
        o1[3 * (32 + c) + 2] = s111 * A.a111z;
    }
}

// cleanup: overflow edges (expected 0) — atomic path, runs after gather
__global__ void cleanup_kernel(
    const int* __restrict__ ovf_count, const int* __restrict__ ovf_list,
    const float* __restrict__ edges, const int* __restrict__ senders,
    const int* __restrict__ receivers,
    const float* __restrict__ nodes0, const float* __restrict__ nodes1,
    const float* __restrict__ c00, const float* __restrict__ c01,
    const float* __restrict__ c10, const float* __restrict__ c11,
    const float* __restrict__ w000, const float* __restrict__ w011,
    const float* __restrict__ w101, const float* __restrict__ w110,
    const float* __restrict__ w111,
    float* __restrict__ out0, float* __restrict__ out1)
{
    int nov = *ovf_count;
    if (nov > 4096) nov = 4096;
    for (int k = threadIdx.x; k < nov; k += blockDim.x) {
        int e = ovf_list[k];
        float ex = edges[3 * e + 0], ey = edges[3 * e + 1], ez = edges[3 * e + 2];
        float r = sqrtf(ex * ex + ey * ey + ez * ez);
        float rbf[5];
#pragma unroll
        for (int b = 0; b < 5; b++) {
            float d = r - 0.875f * (float)b;
            rbf[b] = __expf(-0.7f * d * d);
        }
        int s = senders[e], rc = receivers[e];
        const float* n0p = nodes0 + s * NC;
        const float* n1p = nodes1 + s * NC * 3;
        float* o0 = out0 + rc * 32;
        float* o1 = out1 + rc * 144;
        float pey = Y1CF * ey, pez = Y1CF * ez, pex = Y1CF * ex;
        for (int c = 0; c < NC; c++) {
            float rad00 = 0.f, rad01 = 0.f, rad10 = 0.f, rad11 = 0.f;
#pragma unroll
            for (int b = 0; b < 5; b++) {
                rad00 = fmaf(rbf[b], c00[c * 5 + b], rad00);
                rad01 = fmaf(rbf[b], c01[c * 5 + b], rad01);
                rad10 = fmaf(rbf[b], c10[c * 5 + b], rad10);
                rad11 = fmaf(rbf[b], c11[c * 5 + b], rad11);
            }
            float n0 = n0p[c];
            float n1a = n1p[3 * c + 0], n1b = n1p[3 * c + 1], n1c = n1p[3 * c + 2];
            float f11a = rad11 * pey, f11b = rad11 * pez, f11c = rad11 * pex;
            atomicAdd(&o0[c], w000[c] * n0 * rad00 * Y00F);
            atomicAdd(&o0[16 + c], w110[c] * RS3 * (n1a * f11a + n1b * f11b + n1c * f11c));
            float kA = w011[c] * n0 * rad01;
            atomicAdd(&o1[3 * c + 0], kA * pey);
            atomicAdd(&o1[3 * c + 1], kA * pez);
            atomicAdd(&o1[3 * c + 2], kA * pex);
            float kB = w101[c] * rad10 * Y00F;
            atomicAdd(&o1[3 * (16 + c) + 0], kB * n1a);
            atomicAdd(&o1[3 * (16 + c) + 1], kB * n1b);
            atomicAdd(&o1[3 * (16 + c) + 2], kB * n1c);
            float kC = w111[c] * RS2;
            atomicAdd(&o1[3 * (32 + c) + 0], kC * (n1b * f11c - n1c * f11b));
            atomicAdd(&o1[3 * (32 + c) + 1], kC * (n1c * f11a - n1a * f11c));
            atomicAdd(&o1[3 * (32 + c) + 2], kC * (n1a * f11b - n1b * f11a));
        }
    }
}

// ======================= tier 2: R5 pipeline (hist+scan+scatter) ==========
__global__ void init2_kernel(const float* __restrict__ coords,
                             float* __restrict__ out, int* __restrict__ hist) {
    int i = blockIdx.x * blockDim.x + threadIdx.x;
    if (i < 3 * NN) out[i] = coords[i];
    if (i < NN) hist[i] = 0;
}

__global__ void hist_kernel(const int* __restrict__ receivers,
                            int* __restrict__ hist) {
    int t = blockIdx.x * blockDim.x + threadIdx.x;
    if (t >= E_EDGES / 4) return;
    int4 r = *(const int4*)(receivers + 4 * t);
    atomicAdd(&hist[r.x], 1);
    atomicAdd(&hist[r.y], 1);
    atomicAdd(&hist[r.z], 1);
    atomicAdd(&hist[r.w], 1);
}

__global__ __launch_bounds__(1024) void scan1_kernel(const int* __restrict__ hist,
                                                     int* __restrict__ offs,
                                                     int* __restrict__ btot) {
    __shared__ int sh[1024];
    int t = threadIdx.x, b = blockIdx.x;
    int i = b * 1024 + t;
    int v = (i < NN) ? hist[i] : 0;
    sh[t] = v;
    __syncthreads();
    for (int off = 1; off < 1024; off <<= 1) {
        int x = (t >= off) ? sh[t - off] : 0;
        __syncthreads();
        sh[t] += x;
        __syncthreads();
    }
    int incl = sh[t];
    if (i < NN) offs[i] = incl - v;
    if (t == 1023) btot[b] = incl;
}

__global__ __launch_bounds__(1024) void scan2_kernel(int* __restrict__ offs,
                                                     int* __restrict__ cursor,
                                                     const int* __restrict__ btot,
                                                     int nblk) {
    __shared__ int pre[64];
    int t = threadIdx.x, b = blockIdx.x;
    if (t == 0) {
        int s = 0;
        for (int k = 0; k < nblk; k++) { pre[k] = s; s += btot[k]; }
    }
    __syncthreads();
    int i = b * 1024 + t;
    if (i < NN) {
        int o = offs[i] + pre[b];
        offs[i] = o;
        cursor[i] = o;
    }
    if (b == 0 && t == 0) offs[NN] = E_EDGES;
}

__global__ void scatter_kernel(const float* __restrict__ edges,
                               const int* __restrict__ senders,
                               const int* __restrict__ receivers,
                               int* __restrict__ cursor,
                               nf4* __restrict__ sorted) {
    int e = blockIdx.x * blockDim.x + threadIdx.x;
    if (e >= E_EDGES) return;
    float ex = edges[3 * e + 0];
    float ey = edges[3 * e + 1];
    float ez = edges[3 * e + 2];
    int s  = senders[e];
    int rc = receivers[e];
    int pos = atomicAdd(&cursor[rc], 1);
    nf4 rec = {ex, ey, ez, __int_as_float(s)};
    sorted[pos] = rec;
}

__global__ __launch_bounds__(256) void gather2_kernel(
    const nf4*    __restrict__ sorted,
    const int*    __restrict__ offs,
    const float*  __restrict__ nodes0,
    const float*  __restrict__ nodes1,
    const float*  __restrict__ c00, const float* __restrict__ c01,
    const float*  __restrict__ c10, const float* __restrict__ c11,
    const float*  __restrict__ w000, const float* __restrict__ w011,
    const float*  __restrict__ w101, const float* __restrict__ w110,
    const float*  __restrict__ w111,
    float* __restrict__ out0, float* __restrict__ out1)
{
    int gtid = blockIdx.x * blockDim.x + threadIdx.x;
    int node = gtid >> 6;
    int lane = threadIdx.x & 63;
    int c    = lane & 15;
    int j    = lane >> 4;
    if (node >= NN) return;

    float k00[5], k01[5], k10[5], k11[5];
#pragma unroll
    for (int b = 0; b < 5; b++) {
        k00[b] = c00[c * 5 + b];
        k01[b] = c01[c * 5 + b];
        k10[b] = c10[c * 5 + b];
        k11[b] = c11[c * 5 + b];
    }

    int start = offs[node];
    int end   = offs[node + 1];

    Acc A = {};
    int i = start + j;
    for (; i + 4 < end; i += 8) {
        nf4 r0 = __builtin_nontemporal_load(&sorted[i]);
        nf4 r1 = __builtin_nontemporal_load(&sorted[i + 4]);
        edge_body(r0, nodes0, nodes1, k00, k01, k10, k11, c, A);
        edge_body(r1, nodes0, nodes1, k00, k01, k10, k11, c, A);
    }
    if (i < end) {
        nf4 r0 = __builtin_nontemporal_load(&sorted[i]);
        edge_body(r0, nodes0, nodes1, k00, k01, k10, k11, c, A);
    }

#define RED(v) v += __shfl_xor(v, 16, 64); v += __shfl_xor(v, 32, 64)
    RED(A.a000); RED(A.a110);
    RED(A.a011x); RED(A.a011y); RED(A.a011z);
    RED(A.a101x); RED(A.a101y); RED(A.a101z);
    RED(A.a111x); RED(A.a111y); RED(A.a111z);
#undef RED

    if (j == 0) {
        float s000 = w000[c] * Y00F;
        float s110 = w110[c] * RS3 * Y1CF;
        float s011 = w011[c] * Y1CF;
        float s101 = w101[c] * Y00F;
        float s111 = w111[c] * RS2 * Y1CF;

        out0[node * 32 + c]      = s000 * A.a000;
        out0[node * 32 + 16 + c] = s110 * A.a110;

        float* o1 = out1 + node * 144;
        o1[3 * c + 0] = s011 * A.a011x;
        o1[3 * c + 1] = s011 * A.a011y;
        o1[3 * c + 2] = s011 * A.a011z;
        o1[3 * (16 + c) + 0] = s101 * A.a101x;
        o1[3 * (16 + c) + 1] = s101 * A.a101y;
        o1[3 * (16 + c) + 2] = s101 * A.a101z;
        o1[3 * (32 + c) + 0] = s111 * A.a111x;
        o1[3 * (32 + c) + 1] = s111 * A.a111y;
        o1[3 * (32 + c) + 2] = s111 * A.a111z;
    }
}

// ======================= tier 3: pure atomic fallback =====================
__global__ void init_out_fb(const float* __restrict__ coords,
                            float* __restrict__ out, int out_size) {
    int i = blockIdx.x * blockDim.x + threadIdx.x;
    if (i < 3 * NN) out[i] = coords[i];
    else if (i < out_size) out[i] = 0.0f;
}

__global__ __launch_bounds__(256) void tp_edges_fb(
    const float* __restrict__ edges, const int* __restrict__ senders,
    const int* __restrict__ receivers, const float* __restrict__ nodes0,
    const float* __restrict__ nodes1,
    const float* __restrict__ c00, const float* __restrict__ c01,
    const float* __restrict__ c10, const float* __restrict__ c11,
    const float* __restrict__ w000, const float* __restrict__ w011,
    const float* __restrict__ w101, const float* __restrict__ w110,
    const float* __restrict__ w111,
    float* __restrict__ out0, float* __restrict__ out1) {
    int e = blockIdx.x * blockDim.x + threadIdx.x;
    if (e >= E_EDGES) return;
    float ex = edges[3 * e + 0], ey = edges[3 * e + 1], ez = edges[3 * e + 2];
    float r = sqrtf(ex * ex + ey * ey + ez * ez);
    float rbf[5];
#pragma unroll
    for (int b = 0; b < 5; b++) {
        float d = r - 0.875f * (float)b;
        rbf[b] = __expf(-0.7f * d * d);
    }
    int s = senders[e], rc = receivers[e];
    const float* n0p = nodes0 + s * NC;
    const float* n1p = nodes1 + s * NC * 3;
    float* o0 = out0 + rc * 32;
    float* o1 = out1 + rc * 144;
    float pey = Y1CF * ey, pez = Y1CF * ez, pex = Y1CF * ex;
    for (int c = 0; c < NC; c++) {
        float rad00 = 0.f, rad01 = 0.f, rad10 = 0.f, rad11 = 0.f;
#pragma unroll
        for (int b = 0; b < 5; b++) {
            rad00 = fmaf(rbf[b], c00[c * 5 + b], rad00);
            rad01 = fmaf(rbf[b], c01[c * 5 + b], rad01);
            rad10 = fmaf(rbf[b], c10[c * 5 + b], rad10);
            rad11 = fmaf(rbf[b], c11[c * 5 + b], rad11);
        }
        float n0 = n0p[c];
        float n1a = n1p[3 * c + 0], n1b = n1p[3 * c + 1], n1c = n1p[3 * c + 2];
        float f11a = rad11 * pey, f11b = rad11 * pez, f11c = rad11 * pex;
        atomicAdd(&o0[c], w000[c] * n0 * rad00 * Y00F);
        atomicAdd(&o0[16 + c], w110[c] * RS3 * (n1a * f11a + n1b * f11b + n1c * f11c));
        float kA = w011[c] * n0 * rad01;
        atomicAdd(&o1[3 * c + 0], kA * pey);
        atomicAdd(&o1[3 * c + 1], kA * pez);
        atomicAdd(&o1[3 * c + 2], kA * pex);
        float kB = w101[c] * rad10 * Y00F;
        atomicAdd(&o1[3 * (16 + c) + 0], kB * n1a);
        atomicAdd(&o1[3 * (16 + c) + 1], kB * n1b);
        atomicAdd(&o1[3 * (16 + c) + 2], kB * n1c);
        float kC = w111[c] * RS2;
        atomicAdd(&o1[3 * (32 + c) + 0], kC * (n1b * f11c - n1c * f11b));
        atomicAdd(&o1[3 * (32 + c) + 1], kC * (n1c * f11a - n1a * f11c));
        atomicAdd(&o1[3 * (32 + c) + 2], kC * (n1a * f11b - n1b * f11a));
    }
}

extern "C" void kernel_launch(void* const* d_in, const int* in_sizes, int n_in,
                              void* d_out, int out_size, void* d_ws, size_t ws_size,
                              hipStream_t stream) {
    const float* coords    = (const float*)d_in[0];
    const float* nodes0    = (const float*)d_in[1];
    const float* nodes1    = (const float*)d_in[2];
    const float* edges     = (const float*)d_in[3];
    const int*   senders   = (const int*)  d_in[4];
    const int*   receivers = (const int*)  d_in[5];
    const float* c00       = (const float*)d_in[6];
    const float* c01       = (const float*)d_in[7];
    const float* c10       = (const float*)d_in[8];
    const float* c11       = (const float*)d_in[9];
    const float* w000      = (const float*)d_in[10];
    const float* w011      = (const float*)d_in[11];
    const float* w101      = (const float*)d_in[12];
    const float* w110      = (const float*)d_in[13];
    const float* w111      = (const float*)d_in[14];

    float* out  = (float*)d_out;
    float* out0 = out + 3 * NN;
    float* out1 = out + 3 * NN + NN * 2 * NC;

    size_t bins_bytes = (size_t)NN * PBIN * 16;
    size_t need1 = bins_bytes + (size_t)(NN + 1 + 4096) * 4;
    size_t sorted_bytes = (size_t)E_EDGES * 16;
    size_t need2 = sorted_bytes + (size_t)(3 * NN + 1 + 64) * 4;

    if (ws_size >= need1) {
        nf4* bins      = (nf4*)d_ws;
        int* cnt       = (int*)((char*)d_ws + bins_bytes);  // NN
        int* ovf_count = cnt + NN;                          // 1
        int* ovf_list  = ovf_count + 1;                     // 4096

        init1_kernel<<<(3 * NN + 255) / 256, 256, 0, stream>>>(coords, out, cnt, ovf_count);
        bin_kernel<<<(E_EDGES + 255) / 256, 256, 0, stream>>>(
            edges, senders, receivers, cnt, bins, ovf_count, ovf_list);
        gather1_kernel<<<(NN * 64 + 255) / 256, 256, 0, stream>>>(
            bins, cnt, nodes0, nodes1,
            c00, c01, c10, c11, w000, w011, w101, w110, w111, out0, out1);
        cleanup_kernel<<<1, 256, 0, stream>>>(
            ovf_count, ovf_list, edges, senders, receivers, nodes0, nodes1,
            c00, c01, c10, c11, w000, w011, w101, w110, w111, out0, out1);
    } else if (ws_size >= need2) {
        nf4* sorted = (nf4*)d_ws;
        int* offs   = (int*)((char*)d_ws + sorted_bytes);
        int* cursor = offs + (NN + 1);
        int* hist   = cursor + NN;
        int* btot   = hist + NN;
        const int NBLK = (NN + 1023) / 1024;

        init2_kernel<<<(3 * NN + 255) / 256, 256, 0, stream>>>(coords, out, hist);
        hist_kernel<<<(E_EDGES / 4 + 255) / 256, 256, 0, stream>>>(receivers, hist);
        scan1_kernel<<<NBLK, 1024, 0, stream>>>(hist, offs, btot);
        scan2_kernel<<<NBLK, 1024, 0, stream>>>(offs, cursor, btot, NBLK);
        scatter_kernel<<<(E_EDGES + 255) / 256, 256, 0, stream>>>(
            edges, senders, receivers, cursor, sorted);
        gather2_kernel<<<(NN * 64 + 255) / 256, 256, 0, stream>>>(
            sorted, offs, nodes0, nodes1,
            c00, c01, c10, c11, w000, w011, w101, w110, w111, out0, out1);
    } else {
        init_out_fb<<<(out_size + 255) / 256, 256, 0, stream>>>(coords, out, out_size);
        tp_edges_fb<<<(E_EDGES + 255) / 256, 256, 0, stream>>>(
            edges, senders, receivers, nodes0, nodes1,
            c00, c01, c10, c11, w000, w011, w101, w110, w111, out0, out1);
    }
}